// Round 7
// baseline (336.684 us; speedup 1.0000x reference)
//
#include <hip/hip_runtime.h>
#include <math.h>

#define BB 16
#define TOPK 2000
#define KEEPK 750
#define CAND_CAP 4096
#define EDGE_CAP 8192
#define HIST_BINS 256
#define BIN_BASE 0x3E99u   // (bits of 0.3f) >> 16

// ---------------- kernel 1: scores + per-chunk histogram (16 elems/thread) -------
__global__ __launch_bounds__(256) void k_scores(const float* __restrict__ conf,
                                                const float* __restrict__ iou,
                                                unsigned* __restrict__ sbits,
                                                unsigned* __restrict__ hist,
                                                unsigned* __restrict__ ccount,
                                                unsigned* __restrict__ ecount,
                                                unsigned* __restrict__ tdone,
                                                int N, int nchunk) {
  __shared__ unsigned h[HIST_BINS];
  int b = blockIdx.y;
  int tid = threadIdx.x;
  for (int i = tid; i < HIST_BINS; i += 256) h[i] = 0;
  if (blockIdx.x == 0) {           // zero counters consumed by later kernels
    if (tid == 0) ccount[b] = 0;
    if (tid == 1) ecount[b] = 0;
    if (tid == 2) tdone[b] = 0;
  }
  __syncthreads();
  const float2* c2 = (const float2*)conf + (size_t)b * N;
  const float* iu = iou + (size_t)b * N;
  unsigned* sb = sbits + (size_t)b * N;
  int n0 = blockIdx.x * 4096;
#pragma unroll 4
  for (int k = 0; k < 16; ++k) {
    int n = n0 + k * 256 + tid;
    if (n < N) {
      float2 c = c2[n];
      float m = fmaxf(c.x, c.y);
      // correctly-rounded f32 exp via double to match the reference softmax
      float e0 = (float)exp((double)(c.x - m));
      float e1 = (float)exp((double)(c.y - m));
      float p1 = e1 / (e0 + e1);
      float ic = fminf(fmaxf(iu[n], 0.0f), 1.0f);
      float s = sqrtf(p1 * ic);
      s = (s >= 0.3f) ? s : 0.0f;
      unsigned bits = __float_as_uint(s);
      sb[n] = bits;
      if (bits != 0u) {
        int bin = (int)(bits >> 16) - (int)BIN_BASE;
        bin = bin < 0 ? 0 : (bin > 255 ? 255 : bin);
        atomicAdd(&h[bin], 1u);
      }
    }
  }
  __syncthreads();
  unsigned* hdst = hist + ((size_t)b * nchunk + blockIdx.x) * HIST_BINS;
  for (int i = tid; i < HIST_BINS; i += 256) hdst[i] = h[i];
}

// ---------------- kernel 2: fused threshold + compact (1 atomic per block) -------
__global__ __launch_bounds__(256) void k_compact(const unsigned* __restrict__ sbits,
                                                 const unsigned* __restrict__ hist,
                                                 unsigned* __restrict__ ccount,
                                                 unsigned long long* __restrict__ ckeys,
                                                 int N, int nchunk) {
  __shared__ unsigned sT;
  __shared__ unsigned long long masks[32];
  __shared__ unsigned wioff[32];
  __shared__ unsigned blockbase;
  int b = blockIdx.y;
  int tid = threadIdx.x, lane = tid & 63, wv = tid >> 6;

  if (tid < 64) {
    const unsigned* h = hist + (size_t)b * nchunk * HIST_BINS;
    unsigned v0 = 0, v1 = 0, v2 = 0, v3 = 0;
    int b0 = 255 - (4 * lane + 0), b1 = 255 - (4 * lane + 1);
    int b2 = 255 - (4 * lane + 2), b3 = 255 - (4 * lane + 3);
    for (int c = 0; c < nchunk; ++c) {
      const unsigned* hc = h + c * HIST_BINS;
      v0 += hc[b0]; v1 += hc[b1]; v2 += hc[b2]; v3 += hc[b3];
    }
    unsigned p0 = v0, p1 = p0 + v1, p2 = p1 + v2, p3 = p2 + v3;
    unsigned tot = p3, pre = tot;
    for (int off = 1; off < 64; off <<= 1) {
      unsigned q = __shfl_up(pre, off);
      if (lane >= off) pre += q;
    }
    unsigned excl = pre - tot;
    int kk = -1;
    if (excl + p0 >= TOPK) kk = 0;
    else if (excl + p1 >= TOPK) kk = 1;
    else if (excl + p2 >= TOPK) kk = 2;
    else if (excl + p3 >= TOPK) kk = 3;
    unsigned long long m = __ballot(kk >= 0);
    int bin = 0;
    if (m != 0ull) {
      int fl = __ffsll((unsigned long long)m) - 1;
      int fk = __shfl(kk, fl);
      bin = 255 - (4 * fl + fk);
    }
    if (lane == 0) sT = ((unsigned)(BIN_BASE + (unsigned)bin)) << 16;
  }
  __syncthreads();
  unsigned T = sT;

  const unsigned* sb = sbits + (size_t)b * N;
  int n0 = blockIdx.x * 2048;
  unsigned v[8];
  unsigned long long mk[8];
#pragma unroll
  for (int k = 0; k < 8; ++k) {
    int n = n0 + k * 256 + tid;
    v[k] = (n < N) ? sb[n] : 0u;
    bool p = v[k] >= T;
    mk[k] = __ballot(p);
    if (lane == 0) masks[k * 4 + wv] = mk[k];
  }
  __syncthreads();
  if (tid < 64) {
    unsigned c = (tid < 32) ? (unsigned)__popcll(masks[tid]) : 0u;
    unsigned pre = c;
    for (int off = 1; off < 64; off <<= 1) {
      unsigned q = __shfl_up(pre, off);
      if (lane >= off) pre += q;
    }
    if (tid < 32) wioff[tid] = pre - c;
    if (tid == 31) blockbase = atomicAdd(&ccount[b], pre);
  }
  __syncthreads();
  unsigned base = blockbase;
#pragma unroll
  for (int k = 0; k < 8; ++k) {
    if ((mk[k] >> lane) & 1ull) {
      unsigned pos = base + wioff[k * 4 + wv] +
                     (unsigned)__popcll(mk[k] & ((1ull << lane) - 1ull));
      if (pos < CAND_CAP) {
        int n = n0 + k * 256 + tid;
        ckeys[(size_t)b * CAND_CAP + pos] =
            ((unsigned long long)v[k] << 32) | (unsigned)(~(unsigned)n);
      }
    }
  }
}

// ---- kernel 3a: sort each 1024-chunk (desc for even chunk, asc for odd) ----
__global__ __launch_bounds__(256) void k_sort1(const unsigned* __restrict__ ccount,
                                               unsigned long long* __restrict__ ckeys) {
  __shared__ unsigned long long s[1024];
  int b = blockIdx.x >> 2, chunk = blockIdx.x & 3;
  bool asc = (chunk & 1) != 0;
  int t = threadIdx.x;
  unsigned c = ccount[b];
  if (c > CAND_CAP) c = CAND_CAP;
  unsigned long long* base = ckeys + (size_t)b * CAND_CAP + chunk * 1024;
  int goff = chunk * 1024;
  unsigned long long key[4];
#pragma unroll
  for (int e = 0; e < 4; ++e) {
    int g = goff + 4 * t + e;
    key[e] = (g < (int)c) ? base[4 * t + e] : 0ull;
  }
  for (int k = 2; k <= 1024; k <<= 1) {
    for (int j = k >> 1; j > 0; j >>= 1) {
      if (j >= 256) {
        __syncthreads();
#pragma unroll
        for (int e = 0; e < 4; ++e) s[4 * t + e] = key[e];
        __syncthreads();
        int pbase = (4 * t) ^ j;
        bool own_lo = ((4 * t) & j) == 0;
        bool dir = (((4 * t) & k) == 0) != asc;
        bool keep_max = (own_lo == dir);
#pragma unroll
        for (int e = 0; e < 4; ++e) {
          unsigned long long o = s[pbase + e];
          unsigned long long mx = key[e] > o ? key[e] : o;
          unsigned long long mn = key[e] > o ? o : key[e];
          key[e] = keep_max ? mx : mn;
        }
      } else if (j >= 4) {
        int d = j >> 2;
        bool own_lo = (t & d) == 0;
        bool dir = (((4 * t) & k) == 0) != asc;
        bool keep_max = (own_lo == dir);
#pragma unroll
        for (int e = 0; e < 4; ++e) {
          unsigned long long o = __shfl_xor(key[e], d, 64);
          unsigned long long mx = key[e] > o ? key[e] : o;
          unsigned long long mn = key[e] > o ? o : key[e];
          key[e] = keep_max ? mx : mn;
        }
      } else {
#pragma unroll
        for (int e = 0; e < 4; ++e) {
          int p = e ^ j;
          if (p > e) {
            int i = 4 * t + e;
            bool dir = (((i & k) == 0) != asc);
            bool need = dir ? (key[e] < key[p]) : (key[e] > key[p]);
            if (need) { unsigned long long tmp = key[e]; key[e] = key[p]; key[p] = tmp; }
          }
        }
      }
    }
  }
#pragma unroll
  for (int e = 0; e < 4; ++e) base[4 * t + e] = key[e];
}

// ---- kernel 3b: bitonic merge (k=2048,4096) + balanced decode epilogue ----
__global__ __launch_bounds__(1024) void k_sort2_decode(
    const unsigned long long* __restrict__ ckeys, const float* __restrict__ loc,
    float* __restrict__ top_s, float* __restrict__ out,
    float4* __restrict__ boxes4, int N) {
  __shared__ unsigned long long s[CAND_CAP];
  int b = blockIdx.x;
  int t = threadIdx.x;
  const unsigned long long* src = ckeys + (size_t)b * CAND_CAP;
  unsigned long long key[4];
#pragma unroll
  for (int e = 0; e < 4; ++e) key[e] = src[4 * t + e];
  for (int k = 2048; k <= CAND_CAP; k <<= 1) {
    for (int j = k >> 1; j > 0; j >>= 1) {
      if (j >= 256) {
        __syncthreads();
#pragma unroll
        for (int e = 0; e < 4; ++e) s[4 * t + e] = key[e];
        __syncthreads();
        int pbase = (4 * t) ^ j;
        bool own_lo = ((4 * t) & j) == 0;
        bool dir = ((4 * t) & k) == 0;
        bool keep_max = (own_lo == dir);
#pragma unroll
        for (int e = 0; e < 4; ++e) {
          unsigned long long o = s[pbase + e];
          unsigned long long mx = key[e] > o ? key[e] : o;
          unsigned long long mn = key[e] > o ? o : key[e];
          key[e] = keep_max ? mx : mn;
        }
      } else if (j >= 4) {
        int d = j >> 2;
        bool own_lo = (t & d) == 0;
        bool dir = ((4 * t) & k) == 0;
        bool keep_max = (own_lo == dir);
#pragma unroll
        for (int e = 0; e < 4; ++e) {
          unsigned long long o = __shfl_xor(key[e], d, 64);
          unsigned long long mx = key[e] > o ? key[e] : o;
          unsigned long long mn = key[e] > o ? o : key[e];
          key[e] = keep_max ? mx : mn;
        }
      } else {
#pragma unroll
        for (int e = 0; e < 4; ++e) {
          int p = e ^ j;
          if (p > e) {
            int i = 4 * t + e;
            bool dir = ((i & k) == 0);
            bool need = dir ? (key[e] < key[p]) : (key[e] > key[p]);
            if (need) { unsigned long long tmp = key[e]; key[e] = key[p]; key[p] = tmp; }
          }
        }
      }
    }
  }
  // stage sorted keys to LDS so ALL 1024 threads decode (<=2 rows each)
  __syncthreads();
#pragma unroll
  for (int e = 0; e < 4; ++e) s[4 * t + e] = key[e];
  __syncthreads();
  for (int r = t; r < TOPK; r += 1024) {
    unsigned long long kk = s[r];
    float sv = __uint_as_float((unsigned)(kk >> 32));
    top_s[b * TOPK + r] = sv;
    unsigned idxu = ~(unsigned)kk;
    if (idxu >= (unsigned)N) idxu = 0;  // pad safety
    int i = (int)idxu;
    int off, fw, st, nm, lvl;
    if (i < 97200)       { lvl = 0; off = 0;      fw = 240; st = 8;  nm = 3; }
    else if (i < 113520) { lvl = 1; off = 97200;  fw = 120; st = 16; nm = 2; }
    else if (i < 117600) { lvl = 2; off = 113520; fw = 60;  st = 32; nm = 2; }
    else                 { lvl = 3; off = 117600; fw = 30;  st = 64; nm = 3; }
    int tt = i - off;
    int cell = tt / nm;
    int kms = tt - cell * nm;
    int row = cell / fw;
    int col = cell - row * fw;
    int msv = (lvl == 0) ? (kms == 0 ? 10 : (kms == 1 ? 16 : 24))
            : (lvl == 1) ? (kms == 0 ? 32 : 48)
            : (lvl == 2) ? (kms == 0 ? 64 : 96)
                         : (kms == 0 ? 128 : (kms == 1 ? 192 : 256));
    float cx  = (float)(((double)col + 0.5) * (double)st / 1920.0);
    float cy  = (float)(((double)row + 0.5) * (double)st / 1080.0);
    float skx = (float)((double)msv / 1920.0);
    float sky = (float)((double)msv / 1080.0);
    const float2* lp2 = (const float2*)(loc + ((size_t)b * N + (size_t)i) * 14);
    float l[14];
#pragma unroll
    for (int q = 0; q < 7; ++q) { float2 v = lp2[q]; l[2 * q] = v.x; l[2 * q + 1] = v.y; }
    float cx2 = cx + (l[0] * 0.1f) * skx;
    float cy2 = cy + (l[1] * 0.1f) * sky;
    float wx = skx * expf(l[2] * 0.1f);
    float wy = sky * expf(l[3] * 0.2f);
    float x1 = cx2 - wx * 0.5f, y1 = cy2 - wy * 0.5f;
    float x2 = x1 + wx, y2 = y1 + wy;
    float X1 = x1 * 1920.0f, Y1 = y1 * 1080.0f, X2 = x2 * 1920.0f, Y2 = y2 * 1080.0f;
    float* o = out + ((size_t)b * TOPK + r) * 15;
    o[0] = X1; o[1] = Y1; o[2] = X2; o[3] = Y2;
#pragma unroll
    for (int q = 0; q < 5; ++q) {
      o[4 + 2 * q] = (cx + (l[4 + 2 * q] * 0.1f) * skx) * 1920.0f;
      o[5 + 2 * q] = (cy + (l[5 + 2 * q] * 0.1f) * sky) * 1080.0f;
    }
    boxes4[b * TOPK + r] = make_float4(X1, Y1, X2, Y2);
  }
}

// ---- kernel 4: edges (128x128 triangular tiles) + Jacobi NMS in last tile ----
__global__ __launch_bounds__(128) void k_edges_nms(const float4* __restrict__ boxes4,
                                                   const float* __restrict__ top_s,
                                                   unsigned* __restrict__ ecount,
                                                   unsigned* __restrict__ edges,
                                                   unsigned* __restrict__ tdone,
                                                   float* __restrict__ out) {
  __shared__ float bx1[128], by1[128], bx2[128], by2[128], bta[128];
  __shared__ unsigned loc_e[1024];
  __shared__ unsigned lcnt, gbase;
  __shared__ int is_last;
  int b = blockIdx.y;
  int t = blockIdx.x;                 // 0..135 triangular tile id
  int it = 0;
  while ((it + 1) * (it + 2) / 2 <= t) ++it;
  int jt = t - it * (it + 1) / 2;
  int tid = threadIdx.x;
  if (tid == 0) lcnt = 0;
  int j0 = jt * 128;
  {
    int j = j0 + tid;
    if (j < TOPK) {
      float4 Bj = boxes4[b * TOPK + j];
      bx1[tid] = Bj.x; by1[tid] = Bj.y; bx2[tid] = Bj.z; by2[tid] = Bj.w;
      bta[tid] = 0.3f * (fmaxf(Bj.z - Bj.x, 0.f) * fmaxf(Bj.w - Bj.y, 0.f));
    } else {
      bx1[tid] = 1e30f; by1[tid] = 1e30f; bx2[tid] = -1e30f; by2[tid] = -1e30f;
      bta[tid] = 0.f;
    }
  }
  __syncthreads();
  int i = it * 128 + tid;
  int jmax = 0;
  float4 A4 = make_float4(0, 0, 0, 0);
  float taA = 0.f;
  if (i < TOPK) {
    A4 = boxes4[b * TOPK + i];
    taA = 0.3f * (fmaxf(A4.z - A4.x, 0.f) * fmaxf(A4.w - A4.y, 0.f));
    jmax = i - j0; if (jmax > 128) jmax = 128;
  }
  for (int c = 0; c < jmax; ++c) {
    float xx1 = fmaxf(A4.x, bx1[c]), yy1 = fmaxf(A4.y, by1[c]);
    float xx2 = fminf(A4.z, bx2[c]), yy2 = fminf(A4.w, by2[c]);
    float w = fmaxf(xx2 - xx1, 0.f), h = fmaxf(yy2 - yy1, 0.f);
    float inter = w * h;
    // iou > 0.3  <=>  1.3*inter > 0.3*aA + 0.3*aB + 0.3e-9
    if (inter * 1.3f > taA + bta[c] + 3e-10f) {
      unsigned p = atomicAdd(&lcnt, 1u);
      if (p < 1024u) loc_e[p] = ((unsigned)i << 16) | (unsigned)(j0 + c);
    }
  }
  __syncthreads();
  unsigned cnt = lcnt > 1024u ? 1024u : lcnt;
  if (tid == 0 && cnt) gbase = atomicAdd(&ecount[b], cnt);
  __syncthreads();
  if (cnt) {
    unsigned* dst = edges + (size_t)b * EDGE_CAP;
    for (unsigned e = tid; e < cnt; e += 128) {
      unsigned p = gbase + e;
      if (p < EDGE_CAP) dst[p] = loc_e[e];
    }
  }
  // ---- last-tile-done: the final block for this batch runs the Jacobi NMS ----
  __syncthreads();
  __threadfence();                       // release our edge writes
  if (tid == 0) {
    unsigned done = atomicAdd(&tdone[b], 1u);
    is_last = (done == 135u);
  }
  __syncthreads();
  if (!is_last) return;
  __threadfence();                       // acquire other blocks' edge writes

  __shared__ unsigned long long Am[32], K[32], S[32];
  __shared__ unsigned pref[32];
  __shared__ unsigned ecache[4096];
  __shared__ int changed;
  int lane = tid & 63, wv = tid >> 6;
  for (int base = 0; base < 2048; base += 128) {
    int i2 = base + tid;
    bool act = (i2 < TOPK) && (top_s[b * TOPK + i2] > 0.0f);
    unsigned long long m = __ballot(act);
    if (lane == 0) { int w = (base >> 6) + wv; Am[w] = m; K[w] = m; }
  }
  unsigned E = ecount[b];
  if (E > EDGE_CAP) E = EDGE_CAP;
  unsigned Ec = E > 4096u ? 4096u : E;
  for (unsigned e = tid; e < Ec; e += 128) ecache[e] = edges[(size_t)b * EDGE_CAP + e];
  __syncthreads();
  for (int iter = 0; iter < 32; ++iter) {
    if (tid == 0) changed = 0;
    if (tid < 32) S[tid] = 0ull;
    __syncthreads();
    for (unsigned e = tid; e < Ec; e += 128) {
      unsigned v = ecache[e];
      unsigned ii = v >> 16, j = v & 0xFFFFu;
      if ((K[j >> 6] >> (j & 63)) & 1ull) atomicOr(&S[ii >> 6], 1ull << (ii & 63));
    }
    for (unsigned e = 4096u + tid; e < E; e += 128) {
      unsigned v = edges[(size_t)b * EDGE_CAP + e];
      unsigned ii = v >> 16, j = v & 0xFFFFu;
      if ((K[j >> 6] >> (j & 63)) & 1ull) atomicOr(&S[ii >> 6], 1ull << (ii & 63));
    }
    __syncthreads();
    if (tid < 32) {
      unsigned long long nk = Am[tid] & ~S[tid];
      if (nk != K[tid]) { K[tid] = nk; changed = 1; }
    }
    __syncthreads();
    if (!changed) break;
  }
  if (tid == 0) {
    unsigned acc = 0;
    for (int w = 0; w < 32; ++w) { pref[w] = acc; acc += (unsigned)__popcll(K[w]); }
  }
  __syncthreads();
  for (int base = 0; base < 2048; base += 128) {
    int i2 = base + tid;
    if (i2 < TOPK) {
      int w = i2 >> 6;
      unsigned long long bit = (K[w] >> (i2 & 63)) & 1ull;
      unsigned rank = pref[w] + (unsigned)__popcll(K[w] & ((1ull << (i2 & 63)) - 1ull)) +
                      (unsigned)bit;
      float sv = top_s[b * TOPK + i2];
      out[((size_t)b * TOPK + i2) * 15 + 14] = (bit && rank <= KEEPK) ? sv : 0.0f;
    }
  }
}

extern "C" void kernel_launch(void* const* d_in, const int* in_sizes, int n_in,
                              void* d_out, int out_size, void* d_ws, size_t ws_size,
                              hipStream_t stream) {
  const float* loc  = (const float*)d_in[0];
  const float* conf = (const float*)d_in[1];
  const float* iou  = (const float*)d_in[2];
  float* out = (float*)d_out;
  int N = in_sizes[2] / BB;  // iou is [B,N,1]
  int nchunk = (N + 4095) / 4096;

  char* ws = (char*)d_ws;
  size_t off = 0;
  unsigned* ccount = (unsigned*)(ws + off); off += 64;
  unsigned* ecount = (unsigned*)(ws + off); off += 64;
  unsigned* tdone  = (unsigned*)(ws + off); off += 64;
  off = (off + 255) & ~(size_t)255;
  unsigned* hist   = (unsigned*)(ws + off); off += (size_t)BB * nchunk * HIST_BINS * 4;
  unsigned* sbits  = (unsigned*)(ws + off); off += (size_t)BB * N * 4;
  off = (off + 15) & ~(size_t)15;
  unsigned long long* ckeys = (unsigned long long*)(ws + off); off += (size_t)BB * CAND_CAP * 8;
  float* top_s = (float*)(ws + off);       off += (size_t)BB * TOPK * 4;
  off = (off + 15) & ~(size_t)15;
  float4* boxes4 = (float4*)(ws + off);    off += (size_t)BB * TOPK * 16;
  unsigned* edges = (unsigned*)(ws + off); off += (size_t)BB * EDGE_CAP * 4;

  k_scores<<<dim3(nchunk, BB), 256, 0, stream>>>(conf, iou, sbits, hist, ccount,
                                                 ecount, tdone, N, nchunk);
  k_compact<<<dim3((N + 2047) / 2048, BB), 256, 0, stream>>>(sbits, hist, ccount,
                                                             ckeys, N, nchunk);
  k_sort1<<<BB * 4, 256, 0, stream>>>(ccount, ckeys);
  k_sort2_decode<<<BB, 1024, 0, stream>>>(ckeys, loc, top_s, out, boxes4, N);
  k_edges_nms<<<dim3(136, BB), 128, 0, stream>>>(boxes4, top_s, ecount, edges, tdone, out);
}

// Round 8
// 267.101 us; speedup vs baseline: 1.2605x; 1.2605x over previous
//
#include <hip/hip_runtime.h>
#include <math.h>

#define BB 16
#define TOPK 2000
#define KEEPK 750
#define CAND_CAP 4096
#define EDGE_CAP 8192
#define HIST_BINS 256
#define BIN_BASE 0x3E99u   // (bits of 0.3f) >> 16

// ---------------- kernel 1: scores + per-chunk histogram (16 elems/thread) -------
__global__ __launch_bounds__(256) void k_scores(const float* __restrict__ conf,
                                                const float* __restrict__ iou,
                                                unsigned* __restrict__ sbits,
                                                unsigned* __restrict__ hist,
                                                unsigned* __restrict__ ccount,
                                                unsigned* __restrict__ ecount,
                                                int N, int nchunk) {
  __shared__ unsigned h[HIST_BINS];
  int b = blockIdx.y;
  int tid = threadIdx.x;
  for (int i = tid; i < HIST_BINS; i += 256) h[i] = 0;
  if (blockIdx.x == 0) {           // zero counters consumed by later kernels
    if (tid == 0) ccount[b] = 0;
    if (tid == 1) ecount[b] = 0;
  }
  __syncthreads();
  const float2* c2 = (const float2*)conf + (size_t)b * N;
  const float* iu = iou + (size_t)b * N;
  unsigned* sb = sbits + (size_t)b * N;
  int n0 = blockIdx.x * 4096;
#pragma unroll 4
  for (int k = 0; k < 16; ++k) {
    int n = n0 + k * 256 + tid;
    if (n < N) {
      float2 c = c2[n];
      float m = fmaxf(c.x, c.y);
      // correctly-rounded f32 exp via double to match the reference softmax
      float e0 = (float)exp((double)(c.x - m));
      float e1 = (float)exp((double)(c.y - m));
      float p1 = e1 / (e0 + e1);
      float ic = fminf(fmaxf(iu[n], 0.0f), 1.0f);
      float s = sqrtf(p1 * ic);
      s = (s >= 0.3f) ? s : 0.0f;
      unsigned bits = __float_as_uint(s);
      sb[n] = bits;
      if (bits != 0u) {
        int bin = (int)(bits >> 16) - (int)BIN_BASE;
        bin = bin < 0 ? 0 : (bin > 255 ? 255 : bin);
        atomicAdd(&h[bin], 1u);
      }
    }
  }
  __syncthreads();
  unsigned* hdst = hist + ((size_t)b * nchunk + blockIdx.x) * HIST_BINS;
  for (int i = tid; i < HIST_BINS; i += 256) hdst[i] = h[i];
}

// ---------------- kernel 2: fused threshold + compact (1 atomic per block) -------
__global__ __launch_bounds__(256) void k_compact(const unsigned* __restrict__ sbits,
                                                 const unsigned* __restrict__ hist,
                                                 unsigned* __restrict__ ccount,
                                                 unsigned long long* __restrict__ ckeys,
                                                 int N, int nchunk) {
  __shared__ unsigned sT;
  __shared__ unsigned long long masks[32];
  __shared__ unsigned wioff[32];
  __shared__ unsigned blockbase;
  int b = blockIdx.y;
  int tid = threadIdx.x, lane = tid & 63, wv = tid >> 6;

  if (tid < 64) {
    const unsigned* h = hist + (size_t)b * nchunk * HIST_BINS;
    unsigned v0 = 0, v1 = 0, v2 = 0, v3 = 0;
    int b0 = 255 - (4 * lane + 0), b1 = 255 - (4 * lane + 1);
    int b2 = 255 - (4 * lane + 2), b3 = 255 - (4 * lane + 3);
    for (int c = 0; c < nchunk; ++c) {
      const unsigned* hc = h + c * HIST_BINS;
      v0 += hc[b0]; v1 += hc[b1]; v2 += hc[b2]; v3 += hc[b3];
    }
    unsigned p0 = v0, p1 = p0 + v1, p2 = p1 + v2, p3 = p2 + v3;
    unsigned tot = p3, pre = tot;
    for (int off = 1; off < 64; off <<= 1) {
      unsigned q = __shfl_up(pre, off);
      if (lane >= off) pre += q;
    }
    unsigned excl = pre - tot;
    int kk = -1;
    if (excl + p0 >= TOPK) kk = 0;
    else if (excl + p1 >= TOPK) kk = 1;
    else if (excl + p2 >= TOPK) kk = 2;
    else if (excl + p3 >= TOPK) kk = 3;
    unsigned long long m = __ballot(kk >= 0);
    int bin = 0;
    if (m != 0ull) {
      int fl = __ffsll((unsigned long long)m) - 1;
      int fk = __shfl(kk, fl);
      bin = 255 - (4 * fl + fk);
    }
    if (lane == 0) sT = ((unsigned)(BIN_BASE + (unsigned)bin)) << 16;
  }
  __syncthreads();
  unsigned T = sT;

  const unsigned* sb = sbits + (size_t)b * N;
  int n0 = blockIdx.x * 2048;
  unsigned v[8];
  unsigned long long mk[8];
#pragma unroll
  for (int k = 0; k < 8; ++k) {
    int n = n0 + k * 256 + tid;
    v[k] = (n < N) ? sb[n] : 0u;
    bool p = v[k] >= T;
    mk[k] = __ballot(p);
    if (lane == 0) masks[k * 4 + wv] = mk[k];
  }
  __syncthreads();
  if (tid < 64) {
    unsigned c = (tid < 32) ? (unsigned)__popcll(masks[tid]) : 0u;
    unsigned pre = c;
    for (int off = 1; off < 64; off <<= 1) {
      unsigned q = __shfl_up(pre, off);
      if (lane >= off) pre += q;
    }
    if (tid < 32) wioff[tid] = pre - c;
    if (tid == 31) blockbase = atomicAdd(&ccount[b], pre);
  }
  __syncthreads();
  unsigned base = blockbase;
#pragma unroll
  for (int k = 0; k < 8; ++k) {
    if ((mk[k] >> lane) & 1ull) {
      unsigned pos = base + wioff[k * 4 + wv] +
                     (unsigned)__popcll(mk[k] & ((1ull << lane) - 1ull));
      if (pos < CAND_CAP) {
        int n = n0 + k * 256 + tid;
        ckeys[(size_t)b * CAND_CAP + pos] =
            ((unsigned long long)v[k] << 32) | (unsigned)(~(unsigned)n);
      }
    }
  }
}

// ---- kernel 3a: sort each 1024-chunk (desc for even chunk, asc for odd) ----
__global__ __launch_bounds__(256) void k_sort1(const unsigned* __restrict__ ccount,
                                               unsigned long long* __restrict__ ckeys) {
  __shared__ unsigned long long s[1024];
  int b = blockIdx.x >> 2, chunk = blockIdx.x & 3;
  bool asc = (chunk & 1) != 0;
  int t = threadIdx.x;
  unsigned c = ccount[b];
  if (c > CAND_CAP) c = CAND_CAP;
  unsigned long long* base = ckeys + (size_t)b * CAND_CAP + chunk * 1024;
  int goff = chunk * 1024;
  unsigned long long key[4];
#pragma unroll
  for (int e = 0; e < 4; ++e) {
    int g = goff + 4 * t + e;
    key[e] = (g < (int)c) ? base[4 * t + e] : 0ull;
  }
  for (int k = 2; k <= 1024; k <<= 1) {
    for (int j = k >> 1; j > 0; j >>= 1) {
      if (j >= 256) {
        __syncthreads();
#pragma unroll
        for (int e = 0; e < 4; ++e) s[4 * t + e] = key[e];
        __syncthreads();
        int pbase = (4 * t) ^ j;
        bool own_lo = ((4 * t) & j) == 0;
        bool dir = (((4 * t) & k) == 0) != asc;
        bool keep_max = (own_lo == dir);
#pragma unroll
        for (int e = 0; e < 4; ++e) {
          unsigned long long o = s[pbase + e];
          unsigned long long mx = key[e] > o ? key[e] : o;
          unsigned long long mn = key[e] > o ? o : key[e];
          key[e] = keep_max ? mx : mn;
        }
      } else if (j >= 4) {
        int d = j >> 2;
        bool own_lo = (t & d) == 0;
        bool dir = (((4 * t) & k) == 0) != asc;
        bool keep_max = (own_lo == dir);
#pragma unroll
        for (int e = 0; e < 4; ++e) {
          unsigned long long o = __shfl_xor(key[e], d, 64);
          unsigned long long mx = key[e] > o ? key[e] : o;
          unsigned long long mn = key[e] > o ? o : key[e];
          key[e] = keep_max ? mx : mn;
        }
      } else {
#pragma unroll
        for (int e = 0; e < 4; ++e) {
          int p = e ^ j;
          if (p > e) {
            int i = 4 * t + e;
            bool dir = (((i & k) == 0) != asc);
            bool need = dir ? (key[e] < key[p]) : (key[e] > key[p]);
            if (need) { unsigned long long tmp = key[e]; key[e] = key[p]; key[p] = tmp; }
          }
        }
      }
    }
  }
#pragma unroll
  for (int e = 0; e < 4; ++e) base[4 * t + e] = key[e];
}

// ---- kernel 3b: bitonic merge (k=2048,4096) + balanced decode epilogue ----
__global__ __launch_bounds__(1024) void k_sort2_decode(
    const unsigned long long* __restrict__ ckeys, const float* __restrict__ loc,
    float* __restrict__ top_s, float* __restrict__ out,
    float4* __restrict__ boxes4, int N) {
  __shared__ unsigned long long s[CAND_CAP];
  int b = blockIdx.x;
  int t = threadIdx.x;
  const unsigned long long* src = ckeys + (size_t)b * CAND_CAP;
  unsigned long long key[4];
#pragma unroll
  for (int e = 0; e < 4; ++e) key[e] = src[4 * t + e];
  for (int k = 2048; k <= CAND_CAP; k <<= 1) {
    for (int j = k >> 1; j > 0; j >>= 1) {
      if (j >= 256) {
        __syncthreads();
#pragma unroll
        for (int e = 0; e < 4; ++e) s[4 * t + e] = key[e];
        __syncthreads();
        int pbase = (4 * t) ^ j;
        bool own_lo = ((4 * t) & j) == 0;
        bool dir = ((4 * t) & k) == 0;
        bool keep_max = (own_lo == dir);
#pragma unroll
        for (int e = 0; e < 4; ++e) {
          unsigned long long o = s[pbase + e];
          unsigned long long mx = key[e] > o ? key[e] : o;
          unsigned long long mn = key[e] > o ? o : key[e];
          key[e] = keep_max ? mx : mn;
        }
      } else if (j >= 4) {
        int d = j >> 2;
        bool own_lo = (t & d) == 0;
        bool dir = ((4 * t) & k) == 0;
        bool keep_max = (own_lo == dir);
#pragma unroll
        for (int e = 0; e < 4; ++e) {
          unsigned long long o = __shfl_xor(key[e], d, 64);
          unsigned long long mx = key[e] > o ? key[e] : o;
          unsigned long long mn = key[e] > o ? o : key[e];
          key[e] = keep_max ? mx : mn;
        }
      } else {
#pragma unroll
        for (int e = 0; e < 4; ++e) {
          int p = e ^ j;
          if (p > e) {
            int i = 4 * t + e;
            bool dir = ((i & k) == 0);
            bool need = dir ? (key[e] < key[p]) : (key[e] > key[p]);
            if (need) { unsigned long long tmp = key[e]; key[e] = key[p]; key[p] = tmp; }
          }
        }
      }
    }
  }
  // stage sorted keys to LDS so ALL 1024 threads decode (<=2 rows each)
  __syncthreads();
#pragma unroll
  for (int e = 0; e < 4; ++e) s[4 * t + e] = key[e];
  __syncthreads();
  for (int r = t; r < TOPK; r += 1024) {
    unsigned long long kk = s[r];
    float sv = __uint_as_float((unsigned)(kk >> 32));
    top_s[b * TOPK + r] = sv;
    unsigned idxu = ~(unsigned)kk;
    if (idxu >= (unsigned)N) idxu = 0;  // pad safety
    int i = (int)idxu;
    int off, fw, st, nm, lvl;
    if (i < 97200)       { lvl = 0; off = 0;      fw = 240; st = 8;  nm = 3; }
    else if (i < 113520) { lvl = 1; off = 97200;  fw = 120; st = 16; nm = 2; }
    else if (i < 117600) { lvl = 2; off = 113520; fw = 60;  st = 32; nm = 2; }
    else                 { lvl = 3; off = 117600; fw = 30;  st = 64; nm = 3; }
    int tt = i - off;
    int cell = tt / nm;
    int kms = tt - cell * nm;
    int row = cell / fw;
    int col = cell - row * fw;
    int msv = (lvl == 0) ? (kms == 0 ? 10 : (kms == 1 ? 16 : 24))
            : (lvl == 1) ? (kms == 0 ? 32 : 48)
            : (lvl == 2) ? (kms == 0 ? 64 : 96)
                         : (kms == 0 ? 128 : (kms == 1 ? 192 : 256));
    float cx  = (float)(((double)col + 0.5) * (double)st / 1920.0);
    float cy  = (float)(((double)row + 0.5) * (double)st / 1080.0);
    float skx = (float)((double)msv / 1920.0);
    float sky = (float)((double)msv / 1080.0);
    const float2* lp2 = (const float2*)(loc + ((size_t)b * N + (size_t)i) * 14);
    float l[14];
#pragma unroll
    for (int q = 0; q < 7; ++q) { float2 v = lp2[q]; l[2 * q] = v.x; l[2 * q + 1] = v.y; }
    float cx2 = cx + (l[0] * 0.1f) * skx;
    float cy2 = cy + (l[1] * 0.1f) * sky;
    float wx = skx * expf(l[2] * 0.1f);
    float wy = sky * expf(l[3] * 0.2f);
    float x1 = cx2 - wx * 0.5f, y1 = cy2 - wy * 0.5f;
    float x2 = x1 + wx, y2 = y1 + wy;
    float X1 = x1 * 1920.0f, Y1 = y1 * 1080.0f, X2 = x2 * 1920.0f, Y2 = y2 * 1080.0f;
    float* o = out + ((size_t)b * TOPK + r) * 15;
    o[0] = X1; o[1] = Y1; o[2] = X2; o[3] = Y2;
#pragma unroll
    for (int q = 0; q < 5; ++q) {
      o[4 + 2 * q] = (cx + (l[4 + 2 * q] * 0.1f) * skx) * 1920.0f;
      o[5 + 2 * q] = (cy + (l[5 + 2 * q] * 0.1f) * sky) * 1080.0f;
    }
    boxes4[b * TOPK + r] = make_float4(X1, Y1, X2, Y2);
  }
}

// ---- kernel 4: edges, 128x128 triangular tiles, float4 LDS, 1 atomic/block ----
__global__ __launch_bounds__(128) void k_edges(const float4* __restrict__ boxes4,
                                               unsigned* __restrict__ ecount,
                                               unsigned* __restrict__ edges) {
  __shared__ float4 cb4[128];
  __shared__ float bta[128];
  __shared__ unsigned loc_e[1024];
  __shared__ unsigned lcnt, gbase;
  int b = blockIdx.y;
  int t = blockIdx.x;                 // 0..135 triangular tile id
  int it = 0;
  while ((it + 1) * (it + 2) / 2 <= t) ++it;
  int jt = t - it * (it + 1) / 2;
  int tid = threadIdx.x;
  if (tid == 0) lcnt = 0;
  int j0 = jt * 128;
  {
    int j = j0 + tid;
    if (j < TOPK) {
      float4 Bj = boxes4[b * TOPK + j];
      cb4[tid] = Bj;
      bta[tid] = 0.3f * (fmaxf(Bj.z - Bj.x, 0.f) * fmaxf(Bj.w - Bj.y, 0.f));
    } else {
      cb4[tid] = make_float4(1e30f, 1e30f, -1e30f, -1e30f);
      bta[tid] = 0.f;
    }
  }
  __syncthreads();
  int i = it * 128 + tid;
  int jmax = 0;
  float4 A4 = make_float4(0, 0, 0, 0);
  float taA = 0.f;
  if (i < TOPK) {
    A4 = boxes4[b * TOPK + i];
    taA = 0.3f * (fmaxf(A4.z - A4.x, 0.f) * fmaxf(A4.w - A4.y, 0.f));
    jmax = i - j0; if (jmax > 128) jmax = 128;
  }
  for (int c = 0; c < jmax; ++c) {
    float4 Bx = cb4[c];                 // ds_read_b128
    float xx1 = fmaxf(A4.x, Bx.x), yy1 = fmaxf(A4.y, Bx.y);
    float xx2 = fminf(A4.z, Bx.z), yy2 = fminf(A4.w, Bx.w);
    float w = fmaxf(xx2 - xx1, 0.f), h = fmaxf(yy2 - yy1, 0.f);
    float inter = w * h;
    // iou > 0.3  <=>  1.3*inter > 0.3*aA + 0.3*aB + 0.3e-9
    if (inter * 1.3f > taA + bta[c] + 3e-10f) {
      unsigned p = atomicAdd(&lcnt, 1u);
      if (p < 1024u) loc_e[p] = ((unsigned)i << 16) | (unsigned)(j0 + c);
    }
  }
  __syncthreads();
  unsigned cnt = lcnt > 1024u ? 1024u : lcnt;
  if (tid == 0 && cnt) gbase = atomicAdd(&ecount[b], cnt);
  __syncthreads();
  if (cnt) {
    unsigned* dst = edges + (size_t)b * EDGE_CAP;
    for (unsigned e = tid; e < cnt; e += 128) {
      unsigned p = gbase + e;
      if (p < EDGE_CAP) dst[p] = loc_e[e];
    }
  }
}

// ---- kernel 5: greedy NMS (Jacobi fixpoint, LDS edge cache, early exit) ----
__global__ __launch_bounds__(512) void k_nms(const float* __restrict__ top_s,
                                             const unsigned* __restrict__ ecount,
                                             const unsigned* __restrict__ edges,
                                             float* __restrict__ out) {
  int b = blockIdx.x;
  __shared__ unsigned long long A[32], K[32], S[32];
  __shared__ unsigned pref[32];
  __shared__ unsigned ecache[4096];
  __shared__ int changed;
  int tid = threadIdx.x, lane = tid & 63, wv = tid >> 6;
  for (int base = 0; base < 2048; base += 512) {
    int i = base + tid;
    bool act = (i < TOPK) && (top_s[b * TOPK + i] > 0.0f);
    unsigned long long m = __ballot(act);
    if (lane == 0) { int w = (base >> 6) + wv; A[w] = m; K[w] = m; }
  }
  unsigned E = ecount[b];
  if (E > EDGE_CAP) E = EDGE_CAP;
  unsigned Ec = E > 4096u ? 4096u : E;
  for (unsigned e = tid; e < Ec; e += 512) ecache[e] = edges[(size_t)b * EDGE_CAP + e];
  __syncthreads();
  for (int it = 0; it < 32; ++it) {
    if (tid == 0) changed = 0;
    if (tid < 32) S[tid] = 0ull;
    __syncthreads();
    for (unsigned e = tid; e < Ec; e += 512) {
      unsigned v = ecache[e];
      unsigned i = v >> 16, j = v & 0xFFFFu;
      if ((K[j >> 6] >> (j & 63)) & 1ull) atomicOr(&S[i >> 6], 1ull << (i & 63));
    }
    for (unsigned e = 4096u + tid; e < E; e += 512) {
      unsigned v = edges[(size_t)b * EDGE_CAP + e];
      unsigned i = v >> 16, j = v & 0xFFFFu;
      if ((K[j >> 6] >> (j & 63)) & 1ull) atomicOr(&S[i >> 6], 1ull << (i & 63));
    }
    __syncthreads();
    if (tid < 32) {
      unsigned long long nk = A[tid] & ~S[tid];
      if (nk != K[tid]) { K[tid] = nk; changed = 1; }
    }
    __syncthreads();
    if (!changed) break;
  }
  if (tid == 0) {
    unsigned acc = 0;
    for (int w = 0; w < 32; ++w) { pref[w] = acc; acc += (unsigned)__popcll(K[w]); }
  }
  __syncthreads();
  for (int base = 0; base < 2048; base += 512) {
    int i = base + tid;
    if (i < TOPK) {
      int w = i >> 6;
      unsigned long long bit = (K[w] >> (i & 63)) & 1ull;
      unsigned rank = pref[w] + (unsigned)__popcll(K[w] & ((1ull << (i & 63)) - 1ull)) +
                      (unsigned)bit;
      float sv = top_s[b * TOPK + i];
      out[((size_t)b * TOPK + i) * 15 + 14] = (bit && rank <= KEEPK) ? sv : 0.0f;
    }
  }
}

extern "C" void kernel_launch(void* const* d_in, const int* in_sizes, int n_in,
                              void* d_out, int out_size, void* d_ws, size_t ws_size,
                              hipStream_t stream) {
  const float* loc  = (const float*)d_in[0];
  const float* conf = (const float*)d_in[1];
  const float* iou  = (const float*)d_in[2];
  float* out = (float*)d_out;
  int N = in_sizes[2] / BB;  // iou is [B,N,1]
  int nchunk = (N + 4095) / 4096;

  char* ws = (char*)d_ws;
  size_t off = 0;
  unsigned* ccount = (unsigned*)(ws + off); off += 64;
  unsigned* ecount = (unsigned*)(ws + off); off += 64;
  off = (off + 255) & ~(size_t)255;
  unsigned* hist   = (unsigned*)(ws + off); off += (size_t)BB * nchunk * HIST_BINS * 4;
  unsigned* sbits  = (unsigned*)(ws + off); off += (size_t)BB * N * 4;
  off = (off + 15) & ~(size_t)15;
  unsigned long long* ckeys = (unsigned long long*)(ws + off); off += (size_t)BB * CAND_CAP * 8;
  float* top_s = (float*)(ws + off);       off += (size_t)BB * TOPK * 4;
  off = (off + 15) & ~(size_t)15;
  float4* boxes4 = (float4*)(ws + off);    off += (size_t)BB * TOPK * 16;
  unsigned* edges = (unsigned*)(ws + off); off += (size_t)BB * EDGE_CAP * 4;

  k_scores<<<dim3(nchunk, BB), 256, 0, stream>>>(conf, iou, sbits, hist, ccount,
                                                 ecount, N, nchunk);
  k_compact<<<dim3((N + 2047) / 2048, BB), 256, 0, stream>>>(sbits, hist, ccount,
                                                             ckeys, N, nchunk);
  k_sort1<<<BB * 4, 256, 0, stream>>>(ccount, ckeys);
  k_sort2_decode<<<BB, 1024, 0, stream>>>(ckeys, loc, top_s, out, boxes4, N);
  k_edges<<<dim3(136, BB), 128, 0, stream>>>(boxes4, ecount, edges);
  k_nms<<<BB, 512, 0, stream>>>(top_s, ecount, edges, out);
}